// Round 8
// baseline (284.972 us; speedup 1.0000x reference)
//
#include <hip/hip_runtime.h>
#include <cstdint>
#include <cstddef>

// ---------------------------------------------------------------------------
// ReLA block: y = LN2( (causal_relu( (LN1(x)Wq*s) (LN1(x)Wk)^T ) (LN1(x)Wv)) Wout )
// x: [2,2048,1024] fp32. HEADS=16, DIM_HEAD=64, DIM=1024. Output fp32.
// bf16 MFMA (16x16x32) everywhere, fp32 accumulate.
// R16 = R15 with the workspace-overflow fix: ob32 (f32 attn accumulator)
//      now ALIASES the zb0/zb1 region (58,720,256..75,497,472) instead of
//      extending the footprint past the proven 75.5 MB. Lifetimes are
//      disjoint: ob32 = prep(zero) -> attn(atomicAdd) -> cvt(read);
//      zb0/zb1 = output-GEMM(write, after cvt) -> ln2(read).
//      Split-K attention rationale (R15): ReLU-attn is LINEAR in k (no
//      softmax denominator) -> O = sum_k relu(S) V partitions exactly over
//      K-ranges. Chunk = (row-pair {2a,2a+1}, <=8 K-tiles): 1280 uniform-
//      bounded blocks, 3/CU resident + 512-block backfill queue -> makespan
//      ~= mean (R10/R14 lesson). Grid x=h keeps (h,b) XCD-pinned (R13's
//      L2 property; R14 violated it -> FETCH 4.7x).
// ---------------------------------------------------------------------------

typedef __bf16 bf16_t;
typedef __bf16 bf16x8 __attribute__((ext_vector_type(8)));
typedef __bf16 bf16x4 __attribute__((ext_vector_type(4)));
typedef float  f32x4  __attribute__((ext_vector_type(4)));

#define DEV_INLINE __device__ __forceinline__

// async global->LDS, 16B per lane. LDS dest is wave-uniform base + lane*16.
DEV_INLINE void async_copy16(void* lds, const void* g) {
  __builtin_amdgcn_global_load_lds(
      (__attribute__((address_space(1))) void*)(g),
      (__attribute__((address_space(3))) void*)(lds), 16, 0, 0);
}

// ---------------------------------------------------------------------------
// prep: fused LN1 (blocks 0..4095, also zeroes ob32 row) +
//       wtrans(w_qkv) (4096..4863) + wtrans(w_out) (4864..5119)
// ---------------------------------------------------------------------------
__global__ __launch_bounds__(256) void prep_kernel(
    const float* __restrict__ x, const float* __restrict__ g1,
    const float* __restrict__ b1, bf16_t* __restrict__ xn,
    const float* __restrict__ w_qkv, bf16_t* __restrict__ wqkvT,
    const float* __restrict__ w_out, bf16_t* __restrict__ woutT,
    float* __restrict__ ob32) {
  const int bid = blockIdx.x;
  const int t = threadIdx.x;
  if (bid < 4096) {
    // ---- LN1 row + zero ob32 row ----
    const int w = t >> 6, l = t & 63;
    const float* xr = x + (size_t)bid * 1024;
    float4 v = *(const float4*)(xr + t * 4);
    float4 z; z.x = 0.0f; z.y = 0.0f; z.z = 0.0f; z.w = 0.0f;
    *(float4*)(ob32 + (size_t)bid * 1024 + t * 4) = z;
    float s  = v.x + v.y + v.z + v.w;
    float s2 = v.x * v.x + v.y * v.y + v.z * v.z + v.w * v.w;
    #pragma unroll
    for (int off = 32; off >= 1; off >>= 1) {
      s  += __shfl_down(s, off);
      s2 += __shfl_down(s2, off);
    }
    __shared__ float red[8];
    if (l == 0) { red[w] = s; red[4 + w] = s2; }
    __syncthreads();
    s  = red[0] + red[1] + red[2] + red[3];
    s2 = red[4] + red[5] + red[6] + red[7];
    float mu  = s * (1.0f / 1024.0f);
    float var = s2 * (1.0f / 1024.0f) - mu * mu;
    float rs  = rsqrtf(var + 1e-5f);
    float4 gv = *(const float4*)(g1 + t * 4);
    float4 bv = *(const float4*)(b1 + t * 4);
    bf16x4 o;
    o[0] = (bf16_t)((v.x - mu) * rs * gv.x + bv.x);
    o[1] = (bf16_t)((v.y - mu) * rs * gv.y + bv.y);
    o[2] = (bf16_t)((v.z - mu) * rs * gv.z + bv.z);
    o[3] = (bf16_t)((v.w - mu) * rs * gv.w + bv.w);
    *(bf16x4*)(xn + (size_t)bid * 1024 + t * 4) = o;
  } else {
    // ---- weight transpose+convert: 64x64 tile ----
    const float* wsrc; bf16_t* wdst; int N, tile;
    if (bid < 4864) { wsrc = w_qkv; wdst = wqkvT; N = 3072; tile = bid - 4096; }
    else            { wsrc = w_out; wdst = woutT; N = 1024; tile = bid - 4864; }
    const int ntiles = N >> 6;
    const int n0 = (tile % ntiles) * 64, k0 = (tile / ntiles) * 64;
    __shared__ __align__(16) float tl[64][68];
    #pragma unroll
    for (int c = 0; c < 4; ++c) {
      int idx = c * 256 + t;
      int r = idx >> 4, c4 = (idx & 15) * 4;
      *(float4*)&tl[r][c4] = *(const float4*)(wsrc + (size_t)(k0 + r) * N + n0 + c4);
    }
    __syncthreads();
    #pragma unroll
    for (int c = 0; c < 2; ++c) {
      int idx = c * 256 + t;
      int nl = idx >> 3, kc = (idx & 7) * 8;
      bf16x8 o;
      #pragma unroll
      for (int ii = 0; ii < 8; ++ii) o[ii] = (bf16_t)tl[kc + ii][nl];
      *(bf16x8*)(wdst + (size_t)(n0 + nl) * 1024 + k0 + kc) = o;
    }
  }
}

// ---------------------------------------------------------------------------
// cvt: ob32 (f32 accumulated attn output) -> ao bf16
// ---------------------------------------------------------------------------
__global__ __launch_bounds__(256) void cvt_kernel(
    const float* __restrict__ ob32, bf16_t* __restrict__ ao) {
  const int row = blockIdx.x;
  const int t = threadIdx.x;
  float4 v = *(const float4*)(ob32 + (size_t)row * 1024 + t * 4);
  bf16x4 o;
  o[0] = (bf16_t)v.x; o[1] = (bf16_t)v.y; o[2] = (bf16_t)v.z; o[3] = (bf16_t)v.w;
  *(bf16x4*)(ao + (size_t)row * 1024 + t * 4) = o;
}

// ---------------------------------------------------------------------------
// LN2 (fused split-K add, bf16 partials): z = z0 + z1 -> layernorm -> fp32
// ---------------------------------------------------------------------------
__global__ __launch_bounds__(256) void ln2_kernel(
    const bf16_t* __restrict__ z0, const bf16_t* __restrict__ z1,
    const float* __restrict__ g, const float* __restrict__ bta,
    float* __restrict__ out) {
  const int row = blockIdx.x;
  const int t = threadIdx.x, w = t >> 6, l = t & 63;
  bf16x4 a0 = *(const bf16x4*)(z0 + (size_t)row * 1024 + t * 4);
  bf16x4 a1 = *(const bf16x4*)(z1 + (size_t)row * 1024 + t * 4);
  float4 v;
  v.x = (float)a0[0] + (float)a1[0];
  v.y = (float)a0[1] + (float)a1[1];
  v.z = (float)a0[2] + (float)a1[2];
  v.w = (float)a0[3] + (float)a1[3];
  float s  = v.x + v.y + v.z + v.w;
  float s2 = v.x * v.x + v.y * v.y + v.z * v.z + v.w * v.w;
  #pragma unroll
  for (int off = 32; off >= 1; off >>= 1) {
    s  += __shfl_down(s, off);
    s2 += __shfl_down(s2, off);
  }
  __shared__ float red[8];
  if (l == 0) { red[w] = s; red[4 + w] = s2; }
  __syncthreads();
  s  = red[0] + red[1] + red[2] + red[3];
  s2 = red[4] + red[5] + red[6] + red[7];
  float mu  = s * (1.0f / 1024.0f);
  float var = s2 * (1.0f / 1024.0f) - mu * mu;
  float rs  = rsqrtf(var + 1e-5f);
  float4 gv = *(const float4*)(g + t * 4);
  float4 bv = *(const float4*)(bta + t * 4);
  float4 o;
  o.x = (v.x - mu) * rs * gv.x + bv.x;
  o.y = (v.y - mu) * rs * gv.y + bv.y;
  o.z = (v.z - mu) * rs * gv.z + bv.z;
  o.w = (v.w - mu) * rs * gv.w + bv.w;
  *(float4*)(out + (size_t)row * 1024 + t * 4) = o;
}

// ---------------------------------------------------------------------------
// GEMM: C[M,N] = A[M,1024] @ Bt[N,1024]^T, bf16 in, fp32 acc.
// BK=64, XOR-swizzled staging. KSPLIT=2: kz=0 -> C0, kz=1 -> C1 (bf16
// partials). EPI=1: qkv split epilogue -> q(*0.125)/k bf16 [b,h,2048,64],
// V written TRANSPOSED to C2: vT bf16 [b,h,64,2048] (vtrans fused).
// ---------------------------------------------------------------------------
template <int EPI, int KSPLIT>
__global__ __launch_bounds__(256, 3) void gemm128_kernel(
    const bf16_t* __restrict__ A, const bf16_t* __restrict__ Bt,
    void* __restrict__ C0, void* __restrict__ C1, void* __restrict__ C2) {
  __shared__ __align__(16) bf16_t As[128 * 64];  // 16 KB
  __shared__ __align__(16) bf16_t Bs[128 * 64];  // 16 KB
  const int t = threadIdx.x;
  const int w = t >> 6, l = t & 63, l15 = l & 15, quad = l >> 4;
  const int wy = w >> 1, wx = w & 1;
  const int m0 = blockIdx.y * 128, n0 = blockIdx.x * 128;
  const int kz = (KSPLIT > 1) ? blockIdx.z : 0;
  const int kt0 = kz * (16 / KSPLIT), kt1 = kt0 + (16 / KSPLIT);

  const int r_l = l >> 3;              // row within 8-row chunk
  const int u_src = (l & 7) ^ r_l;     // swizzled source 8-elem unit
  const int rswz = l15 & 7;            // read-side swizzle key

  f32x4 acc[4][4];
  #pragma unroll
  for (int i = 0; i < 4; ++i)
    #pragma unroll
    for (int j = 0; j < 4; ++j) acc[i][j] = (f32x4)0.0f;

  for (int kt = kt0; kt < kt1; ++kt) {
    __syncthreads();
    #pragma unroll
    for (int c = 0; c < 4; ++c) {
      int idx = w * 4 + c;             // 16 chunks of 512 elems
      int row = idx * 8 + r_l;         // 0..127
      async_copy16(&As[idx * 512], A + (size_t)(m0 + row) * 1024 + kt * 64 + u_src * 8);
      async_copy16(&Bs[idx * 512], Bt + (size_t)(n0 + row) * 1024 + kt * 64 + u_src * 8);
    }
    __syncthreads();
    #pragma unroll
    for (int kk = 0; kk < 2; ++kk) {
      bf16x8 af[4], bfr[4];
      #pragma unroll
      for (int i = 0; i < 4; ++i)
        af[i] = *(const bf16x8*)&As[(wy * 64 + i * 16 + l15) * 64 + (((kk * 4 + quad) ^ rswz) * 8)];
      #pragma unroll
      for (int j = 0; j < 4; ++j)
        bfr[j] = *(const bf16x8*)&Bs[(wx * 64 + j * 16 + l15) * 64 + (((kk * 4 + quad) ^ rswz) * 8)];
      #pragma unroll
      for (int i = 0; i < 4; ++i)
        #pragma unroll
        for (int j = 0; j < 4; ++j)
          acc[i][j] = __builtin_amdgcn_mfma_f32_16x16x32_bf16(af[i], bfr[j], acc[i][j], 0, 0, 0);
    }
  }

  if (EPI == 0) {
    bf16_t* C = (bf16_t*)(kz == 0 ? C0 : C1);   // bf16 partial destinations
    #pragma unroll
    for (int i = 0; i < 4; ++i)
      #pragma unroll
      for (int j = 0; j < 4; ++j)
        #pragma unroll
        for (int r = 0; r < 4; ++r) {
          int m = m0 + wy * 64 + i * 16 + quad * 4 + r;
          int n = n0 + wx * 64 + j * 16 + l15;
          C[(size_t)m * 1024 + n] = (bf16_t)acc[i][j][r];
        }
  } else {
    int nb = n0 + wx * 64;
    int which = nb >> 10;              // 0=q, 1=k, 2=v
    int head = (nb & 1023) >> 6;
    const int bq = m0 >> 11;           // batch (uniform per block: m0 multiple of 128)
    const int mb = (m0 & 2047) + wy * 64;
    if (which == 2) {
      // V: write transposed directly -> vT[b,h,d,pos]. acc[i][j][r] has r
      // contiguous in pos, so each lane stores a bf16x4 along pos.
      bf16_t* dst = (bf16_t*)C2 + ((size_t)(bq * 16 + head)) * 64 * 2048;
      #pragma unroll
      for (int i = 0; i < 4; ++i)
        #pragma unroll
        for (int j = 0; j < 4; ++j) {
          bf16x4 pk;
          #pragma unroll
          for (int r = 0; r < 4; ++r) pk[r] = (bf16_t)acc[i][j][r];
          int d = j * 16 + l15;
          int pos = mb + i * 16 + quad * 4;
          *(bf16x4*)(dst + (size_t)d * 2048 + pos) = pk;
        }
    } else {
      bf16_t* dst = which == 0 ? (bf16_t*)C0 : (bf16_t*)C1;
      float sc = which == 0 ? 0.125f : 1.0f;
      #pragma unroll
      for (int i = 0; i < 4; ++i)
        #pragma unroll
        for (int j = 0; j < 4; ++j)
          #pragma unroll
          for (int r = 0; r < 4; ++r) {
            int pos = mb + i * 16 + quad * 4 + r;
            int d = j * 16 + l15;
            dst[(((size_t)(bq * 16 + head)) * 2048 + pos) * 64 + d] =
                (bf16_t)(acc[i][j][r] * sc);
          }
    }
  }
}

// ---------------------------------------------------------------------------
// Causal ReLU attention, R16 (= R15): split-K uniform chunks.
// Block (h=bx, c=by in [0,40), b=bz), 256 thr (4 waves). Chunk c decodes to
// (row-pair a, k-chunk i): rows {2a, 2a+1}, K-tiles [8i, min(8i+8, 2a+2)).
// Wave w = q-slice w (16 q) of BOTH rows. Per tile: 16 ds_read_b128 feed
// 2x(8 S-MFMA + Ss roundtrip + 8 PV-MFMA); both Ss writes before both PV
// reads (R13 overlap). kt==2a diag-masks unit0; kt==2a+1 is unit1-diag
// only. Epilogue: atomicAdd f32 partials into ob32 (linear in k, no
// softmax -> split-K exact). LDS 50.4 KB -> 3 blocks/CU; 1280 blocks =
// 768 resident + 512 backfill queue. Grid x=h -> (h,b) XCD-pinned.
// ---------------------------------------------------------------------------
__global__ __launch_bounds__(256, 3) void attn_kernel(
    const bf16_t* __restrict__ q, const bf16_t* __restrict__ k,
    const bf16_t* __restrict__ vT, float* __restrict__ oacc) {
  __shared__ __align__(16) bf16_t Ks[2][64 * 64];    // dbuf, 16 KB
  __shared__ __align__(16) bf16_t Vts[2][64 * 64];   // 16 KB
  __shared__ __align__(16) bf16_t Ss[4][2][16 * 72]; // [wave][unit] 18.4 KB

  const int h = blockIdx.x, c = blockIdx.y, b = blockIdx.z;
  // decode chunk id -> (row-pair a, k-chunk i)
  int a, i;
  if (c < 4)       { a = c;                i = 0; }
  else if (c < 12) { int e = c - 4;  a = 4 + (e >> 1); i = e & 1; }
  else if (c < 24) { int e = c - 12; int d3 = e / 3; a = 8 + d3; i = e - d3 * 3; }
  else             { int e = c - 24; a = 12 + (e >> 2); i = e & 3; }
  const int kt_lo = 8 * i;
  const int kt_hi = min(8 * i + 8, 2 * a + 2);   // exclusive
  const int rA = 2 * a, rB = 2 * a + 1;          // row-blocks (64 q each)

  const int t = threadIdx.x;
  const int w = t >> 6, l = t & 63, l15 = l & 15, quad = l >> 4;
  const size_t bh = (size_t)(b * 16 + h);

  const int r_l = l >> 3;              // row within 8-row chunk
  const int u_g = (l & 7) ^ r_l;       // swizzled source 8-elem unit
  const int rswz = l15 & 7;            // read-side swizzle key

  // stage one 64x64 K + V tile: 16 async ops over 4 waves
  auto stage_tile = [&](int buf, int kt) {
    #pragma unroll
    for (int cc = 0; cc < 4; ++cc) {
      int op = w * 4 + cc;             // 0..15
      int mK = op >> 3;                // 0 = K, 1 = V
      int idx = op & 7;                // chunk within tile
      int row = idx * 8 + r_l;         // 0..63
      if (mK == 0)
        async_copy16(&Ks[buf][idx * 512],
                     k + (bh * 2048 + kt * 64 + row) * 64 + u_g * 8);
      else
        async_copy16(&Vts[buf][idx * 512],
                     vT + (bh * 64 + row) * 2048 + kt * 64 + u_g * 8);
    }
  };

  // read the staged tile's K/V fragments from LDS (once per tile, per wave)
  auto load_lds = [&](const bf16_t* Kb, const bf16_t* Vb,
                      bf16x8 (&bk)[2][4], bf16x8 (&bv)[2][4]) {
    #pragma unroll
    for (int kk = 0; kk < 2; ++kk)
      #pragma unroll
      for (int tj = 0; tj < 4; ++tj) {
        int u = ((kk * 4 + quad) ^ rswz) * 8;
        bk[kk][tj] = *(const bf16x8*)&Kb[(tj * 16 + l15) * 64 + u];
        bv[kk][tj] = *(const bf16x8*)&Vb[(tj * 16 + l15) * 64 + u];
      }
  };

  bf16x8 qa[2][2];   // [unit][kk]: lane l15 = query row (slice w), k = d
  {
    #pragma unroll
    for (int kk = 0; kk < 2; ++kk) {
      qa[0][kk] = *(const bf16x8*)(q + (bh * 2048 + rA * 64 + w * 16 + l15) * 64 + kk * 32 + quad * 8);
      qa[1][kk] = *(const bf16x8*)(q + (bh * 2048 + rB * 64 + w * 16 + l15) * 64 + kk * 32 + quad * 8);
    }
  }

  // acc[tj] = O^T block: lane col = pos (l15), regs = d = tj*16 + quad*4 + r
  f32x4 acc0[4], acc1[4];
  #pragma unroll
  for (int tj = 0; tj < 4; ++tj) { acc0[tj] = (f32x4)0.0f; acc1[tj] = (f32x4)0.0f; }

  // S^T matmul into registers (no LDS)
  auto sU = [&](f32x4 (&sacc)[4], bf16x8 (&qf)[2], bf16x8 (&bk)[2][4]) {
    #pragma unroll
    for (int tj = 0; tj < 4; ++tj) sacc[tj] = (f32x4)0.0f;
    #pragma unroll
    for (int kk = 0; kk < 2; ++kk)
      #pragma unroll
      for (int tj = 0; tj < 4; ++tj)
        sacc[tj] = __builtin_amdgcn_mfma_f32_16x16x32_bf16(bk[kk][tj], qf[kk], sacc[tj], 0, 0, 0);
  };
  // relu + mask + packed Ss write (wave-private 16-row region)
  auto wU = [&](f32x4 (&sacc)[4], bool dg, bf16_t* SsBuf) {
    #pragma unroll
    for (int tj = 0; tj < 4; ++tj) {
      bf16x4 pk;
      #pragma unroll
      for (int r = 0; r < 4; ++r) {
        float v = fmaxf(sacc[tj][r], 0.0f);
        if (dg && (tj * 16 + quad * 4 + r > w * 16 + l15)) v = 0.0f;
        pk[r] = (bf16_t)v;
      }
      *(bf16x4*)&SsBuf[l15 * 72 + tj * 16 + quad * 4] = pk;
    }
  };
  // PV: read Ss as B-fragment, O^T += V^T.S
  auto pU = [&](f32x4 (&accr)[4], bf16x8 (&bv)[2][4], const bf16_t* SsBuf) {
    #pragma unroll
    for (int kk = 0; kk < 2; ++kk) {
      bf16x8 as_ = *(const bf16x8*)&SsBuf[l15 * 72 + kk * 32 + quad * 8];
      #pragma unroll
      for (int tj = 0; tj < 4; ++tj)
        accr[tj] = __builtin_amdgcn_mfma_f32_16x16x32_bf16(bv[kk][tj], as_, accr[tj], 0, 0, 0);
    }
  };

  bf16_t* SsA = &Ss[w][0][0];
  bf16_t* SsB = &Ss[w][1][0];

  stage_tile(0, kt_lo);
  for (int kt = kt_lo; kt < kt_hi; ++kt) {
    __syncthreads();  // drains this buffer's async loads; fences reuse
    if (kt + 1 < kt_hi) stage_tile((kt + 1 - kt_lo) & 1, kt + 1);
    const int buf = (kt - kt_lo) & 1;
    bf16x8 bk[2][4], bv[2][4];
    load_lds(Ks[buf], Vts[buf], bk, bv);
    if (kt < rB) {
      // both units (unit0 diag-masked on kt == rA; earlier chunks kt < rA)
      f32x4 s0[4], s1[4];
      sU(s0, qa[0], bk);
      sU(s1, qa[1], bk);
      wU(s0, kt == rA, SsA);           // both Ss writes first...
      wU(s1, false, SsB);
      pU(acc0, bv, SsA);               // ...then both PV streams (overlap)
      pU(acc1, bv, SsB);
    } else {
      // kt == rB: unit1's diagonal tile only
      f32x4 s1[4];
      sU(s1, qa[1], bk);
      wU(s1, true, SsB);
      pU(acc1, bv, SsB);
    }
  }

  // epilogue: atomicAdd f32 partials -> oacc[b][pos][h*64+d]
  const int posA = rA * 64 + w * 16 + l15;
  const int posB = rB * 64 + w * 16 + l15;
  float* baseA = oacc + ((size_t)b * 2048 + posA) * 1024 + h * 64;
  float* baseB = oacc + ((size_t)b * 2048 + posB) * 1024 + h * 64;
  #pragma unroll
  for (int tj = 0; tj < 4; ++tj)
    #pragma unroll
    for (int r = 0; r < 4; ++r) {
      int d = tj * 16 + quad * 4 + r;
      atomicAdd(baseA + d, acc0[tj][r]);
      atomicAdd(baseB + d, acc1[tj][r]);
    }
}

// ---------------------------------------------------------------------------
// launch
// ---------------------------------------------------------------------------
extern "C" void kernel_launch(void* const* d_in, const int* in_sizes, int n_in,
                              void* d_out, int out_size, void* d_ws, size_t ws_size,
                              hipStream_t stream) {
  (void)in_sizes; (void)n_in; (void)out_size; (void)ws_size;
  const float* x     = (const float*)d_in[0];
  const float* ln1_g = (const float*)d_in[1];
  const float* ln1_b = (const float*)d_in[2];
  const float* w_qkv = (const float*)d_in[3];
  const float* w_out = (const float*)d_in[4];
  const float* ln2_g = (const float*)d_in[5];
  const float* ln2_b = (const float*)d_in[6];
  float* out = (float*)d_out;

  char* ws = (char*)d_ws;
  bf16_t* xn     = (bf16_t*)(ws + 0);          //  8,388,608  [4096,1024]
  bf16_t* wqkvT  = (bf16_t*)(ws + 8388608);    //  6,291,456  [3072,1024]
  bf16_t* woutT  = (bf16_t*)(ws + 14680064);   //  2,097,152  [1024,1024]
  bf16_t* qb     = (bf16_t*)(ws + 16777216);   //  8,388,608  [2,16,2048,64]
  bf16_t* kb     = (bf16_t*)(ws + 25165824);   //  8,388,608
  bf16_t* vTb    = (bf16_t*)(ws + 41943040);   //  8,388,608  [2,16,64,2048] (written by QKV epilogue)
  bf16_t* ao     = (bf16_t*)(ws + 50331648);   //  8,388,608  [4096,1024]
  // ob32 ALIASES the zb0/zb1 region (16 MB): disjoint lifetimes —
  // ob32: prep(zero) -> attn(atomicAdd) -> cvt(read);
  // zb0/zb1: output-GEMM(write, after cvt) -> ln2(read).
  float*  ob32   = (float*) (ws + 58720256);   // 16,777,216  [4096,1024] f32 attn accum
  bf16_t* zb0    = (bf16_t*)(ws + 58720256);   //  8,388,608  [4096,1024] bf16 partial
  bf16_t* zb1    = (bf16_t*)(ws + 67108864);   //  8,388,608  bf16 partial

  prep_kernel<<<5120, 256, 0, stream>>>(x, ln1_g, ln1_b, xn, w_qkv, wqkvT, w_out, woutT, ob32);
  gemm128_kernel<1, 1><<<dim3(24, 32), 256, 0, stream>>>(xn, wqkvT, qb, kb, vTb);
  attn_kernel<<<dim3(16, 40, 2), 256, 0, stream>>>(qb, kb, vTb, ob32);
  cvt_kernel<<<4096, 256, 0, stream>>>(ob32, ao);
  gemm128_kernel<0, 2><<<dim3(8, 32, 2), 256, 0, stream>>>(ao, woutT, zb0, zb1, nullptr);
  ln2_kernel<<<4096, 256, 0, stream>>>(zb0, zb1, ln2_g, ln2_b, out);
}

// Round 9
// 180.280 us; speedup vs baseline: 1.5807x; 1.5807x over previous
//
#include <hip/hip_runtime.h>
#include <cstdint>
#include <cstddef>

// ---------------------------------------------------------------------------
// ReLA block: y = LN2( (causal_relu( (LN1(x)Wq*s) (LN1(x)Wk)^T ) (LN1(x)Wv)) Wout )
// x: [2,2048,1024] fp32. HEADS=16, DIM_HEAD=64, DIM=1024. Output fp32.
// bf16 MFMA (16x16x32) everywhere, fp32 accumulate.
// R17 = R14's time-uniform attn + CORRECT XCD placement (the two fixes
//      finally combined):
//      - R14 structure: block (256 thr, 4 waves) owns rows {m, 31-m};
//        every wave carries a lo unit (kt<=m) and hi unit (all 32-m tiles)
//        -> no wave parks at barriers (R13's occ-16% flaw).
//      - R13 placement: grid (x=h, y=m, z=b) -> linear id mod 8 = h mod 8,
//        so each (h,b)'s K/V stays on ONE XCD's L2 (R14 put m in x ->
//        FETCH 58 MB, 4.7x overfetch, HBM-starved).
//      - R16's atomic split-K is dead: 179 MB WRITE, 140 µs. Reverted.
//      Co-located adjacent ids share m -> identical block duration.
// ---------------------------------------------------------------------------

typedef __bf16 bf16_t;
typedef __bf16 bf16x8 __attribute__((ext_vector_type(8)));
typedef __bf16 bf16x4 __attribute__((ext_vector_type(4)));
typedef float  f32x4  __attribute__((ext_vector_type(4)));

#define DEV_INLINE __device__ __forceinline__

// async global->LDS, 16B per lane. LDS dest is wave-uniform base + lane*16.
DEV_INLINE void async_copy16(void* lds, const void* g) {
  __builtin_amdgcn_global_load_lds(
      (__attribute__((address_space(1))) void*)(g),
      (__attribute__((address_space(3))) void*)(lds), 16, 0, 0);
}

// ---------------------------------------------------------------------------
// prep: fused LN1 (blocks 0..4095) + wtrans(w_qkv) (4096..4863) +
//       wtrans(w_out) (4864..5119)
// ---------------------------------------------------------------------------
__global__ __launch_bounds__(256) void prep_kernel(
    const float* __restrict__ x, const float* __restrict__ g1,
    const float* __restrict__ b1, bf16_t* __restrict__ xn,
    const float* __restrict__ w_qkv, bf16_t* __restrict__ wqkvT,
    const float* __restrict__ w_out, bf16_t* __restrict__ woutT) {
  const int bid = blockIdx.x;
  const int t = threadIdx.x;
  if (bid < 4096) {
    // ---- LN1 row ----
    const int w = t >> 6, l = t & 63;
    const float* xr = x + (size_t)bid * 1024;
    float4 v = *(const float4*)(xr + t * 4);
    float s  = v.x + v.y + v.z + v.w;
    float s2 = v.x * v.x + v.y * v.y + v.z * v.z + v.w * v.w;
    #pragma unroll
    for (int off = 32; off >= 1; off >>= 1) {
      s  += __shfl_down(s, off);
      s2 += __shfl_down(s2, off);
    }
    __shared__ float red[8];
    if (l == 0) { red[w] = s; red[4 + w] = s2; }
    __syncthreads();
    s  = red[0] + red[1] + red[2] + red[3];
    s2 = red[4] + red[5] + red[6] + red[7];
    float mu  = s * (1.0f / 1024.0f);
    float var = s2 * (1.0f / 1024.0f) - mu * mu;
    float rs  = rsqrtf(var + 1e-5f);
    float4 gv = *(const float4*)(g1 + t * 4);
    float4 bv = *(const float4*)(b1 + t * 4);
    bf16x4 o;
    o[0] = (bf16_t)((v.x - mu) * rs * gv.x + bv.x);
    o[1] = (bf16_t)((v.y - mu) * rs * gv.y + bv.y);
    o[2] = (bf16_t)((v.z - mu) * rs * gv.z + bv.z);
    o[3] = (bf16_t)((v.w - mu) * rs * gv.w + bv.w);
    *(bf16x4*)(xn + (size_t)bid * 1024 + t * 4) = o;
  } else {
    // ---- weight transpose+convert: 64x64 tile ----
    const float* wsrc; bf16_t* wdst; int N, tile;
    if (bid < 4864) { wsrc = w_qkv; wdst = wqkvT; N = 3072; tile = bid - 4096; }
    else            { wsrc = w_out; wdst = woutT; N = 1024; tile = bid - 4864; }
    const int ntiles = N >> 6;
    const int n0 = (tile % ntiles) * 64, k0 = (tile / ntiles) * 64;
    __shared__ __align__(16) float tl[64][68];
    #pragma unroll
    for (int c = 0; c < 4; ++c) {
      int idx = c * 256 + t;
      int r = idx >> 4, c4 = (idx & 15) * 4;
      *(float4*)&tl[r][c4] = *(const float4*)(wsrc + (size_t)(k0 + r) * N + n0 + c4);
    }
    __syncthreads();
    #pragma unroll
    for (int c = 0; c < 2; ++c) {
      int idx = c * 256 + t;
      int nl = idx >> 3, kc = (idx & 7) * 8;
      bf16x8 o;
      #pragma unroll
      for (int ii = 0; ii < 8; ++ii) o[ii] = (bf16_t)tl[kc + ii][nl];
      *(bf16x8*)(wdst + (size_t)(n0 + nl) * 1024 + k0 + kc) = o;
    }
  }
}

// ---------------------------------------------------------------------------
// LN2 (fused split-K add, bf16 partials): z = z0 + z1 -> layernorm -> fp32
// ---------------------------------------------------------------------------
__global__ __launch_bounds__(256) void ln2_kernel(
    const bf16_t* __restrict__ z0, const bf16_t* __restrict__ z1,
    const float* __restrict__ g, const float* __restrict__ bta,
    float* __restrict__ out) {
  const int row = blockIdx.x;
  const int t = threadIdx.x, w = t >> 6, l = t & 63;
  bf16x4 a0 = *(const bf16x4*)(z0 + (size_t)row * 1024 + t * 4);
  bf16x4 a1 = *(const bf16x4*)(z1 + (size_t)row * 1024 + t * 4);
  float4 v;
  v.x = (float)a0[0] + (float)a1[0];
  v.y = (float)a0[1] + (float)a1[1];
  v.z = (float)a0[2] + (float)a1[2];
  v.w = (float)a0[3] + (float)a1[3];
  float s  = v.x + v.y + v.z + v.w;
  float s2 = v.x * v.x + v.y * v.y + v.z * v.z + v.w * v.w;
  #pragma unroll
  for (int off = 32; off >= 1; off >>= 1) {
    s  += __shfl_down(s, off);
    s2 += __shfl_down(s2, off);
  }
  __shared__ float red[8];
  if (l == 0) { red[w] = s; red[4 + w] = s2; }
  __syncthreads();
  s  = red[0] + red[1] + red[2] + red[3];
  s2 = red[4] + red[5] + red[6] + red[7];
  float mu  = s * (1.0f / 1024.0f);
  float var = s2 * (1.0f / 1024.0f) - mu * mu;
  float rs  = rsqrtf(var + 1e-5f);
  float4 gv = *(const float4*)(g + t * 4);
  float4 bv = *(const float4*)(bta + t * 4);
  float4 o;
  o.x = (v.x - mu) * rs * gv.x + bv.x;
  o.y = (v.y - mu) * rs * gv.y + bv.y;
  o.z = (v.z - mu) * rs * gv.z + bv.z;
  o.w = (v.w - mu) * rs * gv.w + bv.w;
  *(float4*)(out + (size_t)row * 1024 + t * 4) = o;
}

// ---------------------------------------------------------------------------
// GEMM: C[M,N] = A[M,1024] @ Bt[N,1024]^T, bf16 in, fp32 acc.
// BK=64, XOR-swizzled staging. KSPLIT=2: kz=0 -> C0, kz=1 -> C1 (bf16
// partials). EPI=1: qkv split epilogue -> q(*0.125)/k bf16 [b,h,2048,64],
// V written TRANSPOSED to C2: vT bf16 [b,h,64,2048] (vtrans fused).
// ---------------------------------------------------------------------------
template <int EPI, int KSPLIT>
__global__ __launch_bounds__(256, 3) void gemm128_kernel(
    const bf16_t* __restrict__ A, const bf16_t* __restrict__ Bt,
    void* __restrict__ C0, void* __restrict__ C1, void* __restrict__ C2) {
  __shared__ __align__(16) bf16_t As[128 * 64];  // 16 KB
  __shared__ __align__(16) bf16_t Bs[128 * 64];  // 16 KB
  const int t = threadIdx.x;
  const int w = t >> 6, l = t & 63, l15 = l & 15, quad = l >> 4;
  const int wy = w >> 1, wx = w & 1;
  const int m0 = blockIdx.y * 128, n0 = blockIdx.x * 128;
  const int kz = (KSPLIT > 1) ? blockIdx.z : 0;
  const int kt0 = kz * (16 / KSPLIT), kt1 = kt0 + (16 / KSPLIT);

  const int r_l = l >> 3;              // row within 8-row chunk
  const int u_src = (l & 7) ^ r_l;     // swizzled source 8-elem unit
  const int rswz = l15 & 7;            // read-side swizzle key

  f32x4 acc[4][4];
  #pragma unroll
  for (int i = 0; i < 4; ++i)
    #pragma unroll
    for (int j = 0; j < 4; ++j) acc[i][j] = (f32x4)0.0f;

  for (int kt = kt0; kt < kt1; ++kt) {
    __syncthreads();
    #pragma unroll
    for (int c = 0; c < 4; ++c) {
      int idx = w * 4 + c;             // 16 chunks of 512 elems
      int row = idx * 8 + r_l;         // 0..127
      async_copy16(&As[idx * 512], A + (size_t)(m0 + row) * 1024 + kt * 64 + u_src * 8);
      async_copy16(&Bs[idx * 512], Bt + (size_t)(n0 + row) * 1024 + kt * 64 + u_src * 8);
    }
    __syncthreads();
    #pragma unroll
    for (int kk = 0; kk < 2; ++kk) {
      bf16x8 af[4], bfr[4];
      #pragma unroll
      for (int i = 0; i < 4; ++i)
        af[i] = *(const bf16x8*)&As[(wy * 64 + i * 16 + l15) * 64 + (((kk * 4 + quad) ^ rswz) * 8)];
      #pragma unroll
      for (int j = 0; j < 4; ++j)
        bfr[j] = *(const bf16x8*)&Bs[(wx * 64 + j * 16 + l15) * 64 + (((kk * 4 + quad) ^ rswz) * 8)];
      #pragma unroll
      for (int i = 0; i < 4; ++i)
        #pragma unroll
        for (int j = 0; j < 4; ++j)
          acc[i][j] = __builtin_amdgcn_mfma_f32_16x16x32_bf16(af[i], bfr[j], acc[i][j], 0, 0, 0);
    }
  }

  if (EPI == 0) {
    bf16_t* C = (bf16_t*)(kz == 0 ? C0 : C1);   // bf16 partial destinations
    #pragma unroll
    for (int i = 0; i < 4; ++i)
      #pragma unroll
      for (int j = 0; j < 4; ++j)
        #pragma unroll
        for (int r = 0; r < 4; ++r) {
          int m = m0 + wy * 64 + i * 16 + quad * 4 + r;
          int n = n0 + wx * 64 + j * 16 + l15;
          C[(size_t)m * 1024 + n] = (bf16_t)acc[i][j][r];
        }
  } else {
    int nb = n0 + wx * 64;
    int which = nb >> 10;              // 0=q, 1=k, 2=v
    int head = (nb & 1023) >> 6;
    const int bq = m0 >> 11;           // batch (uniform per block: m0 multiple of 128)
    const int mb = (m0 & 2047) + wy * 64;
    if (which == 2) {
      // V: write transposed directly -> vT[b,h,d,pos]. acc[i][j][r] has r
      // contiguous in pos, so each lane stores a bf16x4 along pos.
      bf16_t* dst = (bf16_t*)C2 + ((size_t)(bq * 16 + head)) * 64 * 2048;
      #pragma unroll
      for (int i = 0; i < 4; ++i)
        #pragma unroll
        for (int j = 0; j < 4; ++j) {
          bf16x4 pk;
          #pragma unroll
          for (int r = 0; r < 4; ++r) pk[r] = (bf16_t)acc[i][j][r];
          int d = j * 16 + l15;
          int pos = mb + i * 16 + quad * 4;
          *(bf16x4*)(dst + (size_t)d * 2048 + pos) = pk;
        }
    } else {
      bf16_t* dst = which == 0 ? (bf16_t*)C0 : (bf16_t*)C1;
      float sc = which == 0 ? 0.125f : 1.0f;
      #pragma unroll
      for (int i = 0; i < 4; ++i)
        #pragma unroll
        for (int j = 0; j < 4; ++j)
          #pragma unroll
          for (int r = 0; r < 4; ++r) {
            int pos = mb + i * 16 + quad * 4 + r;
            int d = j * 16 + l15;
            dst[(((size_t)(bq * 16 + head)) * 2048 + pos) * 64 + d] =
                (bf16_t)(acc[i][j][r] * sc);
          }
    }
  }
}

// ---------------------------------------------------------------------------
// Causal ReLU attention, R17: time-uniform waves + XCD-pinned placement.
// Block (h=bx, m=by, b=bz), 256 threads (4 waves). Block owns row-blocks
// r_lo=m, r_hi=31-m. Wave w handles q-slice w (16 q) of BOTH: unit-lo
// active for kt<=m, unit-hi for all kt in 0..31-m -> every wave busy to
// the end (no barrier parking). Per-unit per-wave Ss buffers: both Ss
// writes before both PV reads (round-trip overlap). 1 tile staged/iter
// (dbuf). Grid linear id mod 8 = h mod 8 -> each (h,b)'s 512 KB K/V pinned
// to one XCD L2 (2 MB/XCD live). Co-located adjacent ids share m ->
// identical duration. LDS 50.4 KB; 512 blocks = 2/CU.
// ---------------------------------------------------------------------------
__global__ __launch_bounds__(256, 2) void attn_kernel(
    const bf16_t* __restrict__ q, const bf16_t* __restrict__ k,
    const bf16_t* __restrict__ vT, bf16_t* __restrict__ out) {
  __shared__ __align__(16) bf16_t Ks[2][64 * 64];    // dbuf, 16 KB
  __shared__ __align__(16) bf16_t Vts[2][64 * 64];   // 16 KB
  __shared__ __align__(16) bf16_t Ss[4][2][16 * 72]; // [wave][unit] 18.4 KB

  const int h = blockIdx.x, m = blockIdx.y, b = blockIdx.z;
  const int t = threadIdx.x;
  const int w = t >> 6, l = t & 63, l15 = l & 15, quad = l >> 4;
  const size_t bh = (size_t)(b * 16 + h);
  const int r_lo = m, r_hi = 31 - m;   // row-blocks (64 q each)
  const int niter = 32 - m;            // tiles 0..31-m

  const int r_l = l >> 3;              // row within 8-row chunk
  const int u_g = (l & 7) ^ r_l;       // swizzled source 8-elem unit
  const int rswz = l15 & 7;            // read-side swizzle key

  // stage one 64x64 K + V tile: 16 async ops over 4 waves
  auto stage_tile = [&](int buf, int kt) {
    #pragma unroll
    for (int c = 0; c < 4; ++c) {
      int op = w * 4 + c;              // 0..15
      int mK = op >> 3;                // 0 = K, 1 = V
      int idx = op & 7;                // chunk within tile
      int row = idx * 8 + r_l;         // 0..63
      if (mK == 0)
        async_copy16(&Ks[buf][idx * 512],
                     k + (bh * 2048 + kt * 64 + row) * 64 + u_g * 8);
      else
        async_copy16(&Vts[buf][idx * 512],
                     vT + (bh * 64 + row) * 2048 + kt * 64 + u_g * 8);
    }
  };

  // read the staged tile's K/V fragments from LDS (once per tile, per wave)
  auto load_lds = [&](const bf16_t* Kb, const bf16_t* Vb,
                      bf16x8 (&bk)[2][4], bf16x8 (&bv)[2][4]) {
    #pragma unroll
    for (int kk = 0; kk < 2; ++kk)
      #pragma unroll
      for (int tj = 0; tj < 4; ++tj) {
        int u = ((kk * 4 + quad) ^ rswz) * 8;
        bk[kk][tj] = *(const bf16x8*)&Kb[(tj * 16 + l15) * 64 + u];
        bv[kk][tj] = *(const bf16x8*)&Vb[(tj * 16 + l15) * 64 + u];
      }
  };

  bf16x8 qa[2][2];   // [unit][kk]: lane l15 = query row (slice w), k = d
  {
    #pragma unroll
    for (int kk = 0; kk < 2; ++kk) {
      qa[0][kk] = *(const bf16x8*)(q + (bh * 2048 + r_lo * 64 + w * 16 + l15) * 64 + kk * 32 + quad * 8);
      qa[1][kk] = *(const bf16x8*)(q + (bh * 2048 + r_hi * 64 + w * 16 + l15) * 64 + kk * 32 + quad * 8);
    }
  }

  // acc[tj] = O^T block: lane col = pos (l15), regs = d = tj*16 + quad*4 + r
  f32x4 acc0[4], acc1[4];
  #pragma unroll
  for (int tj = 0; tj < 4; ++tj) { acc0[tj] = (f32x4)0.0f; acc1[tj] = (f32x4)0.0f; }

  // S^T matmul into registers (no LDS)
  auto sU = [&](f32x4 (&sacc)[4], bf16x8 (&qf)[2], bf16x8 (&bk)[2][4]) {
    #pragma unroll
    for (int tj = 0; tj < 4; ++tj) sacc[tj] = (f32x4)0.0f;
    #pragma unroll
    for (int kk = 0; kk < 2; ++kk)
      #pragma unroll
      for (int tj = 0; tj < 4; ++tj)
        sacc[tj] = __builtin_amdgcn_mfma_f32_16x16x32_bf16(bk[kk][tj], qf[kk], sacc[tj], 0, 0, 0);
  };
  // relu + mask + packed Ss write (wave-private 16-row region)
  auto wU = [&](f32x4 (&sacc)[4], bool dg, bf16_t* SsBuf) {
    #pragma unroll
    for (int tj = 0; tj < 4; ++tj) {
      bf16x4 pk;
      #pragma unroll
      for (int r = 0; r < 4; ++r) {
        float v = fmaxf(sacc[tj][r], 0.0f);
        if (dg && (tj * 16 + quad * 4 + r > w * 16 + l15)) v = 0.0f;
        pk[r] = (bf16_t)v;
      }
      *(bf16x4*)&SsBuf[l15 * 72 + tj * 16 + quad * 4] = pk;
    }
  };
  // PV: read Ss as B-fragment, O^T += V^T.S
  auto pU = [&](f32x4 (&accr)[4], bf16x8 (&bv)[2][4], const bf16_t* SsBuf) {
    #pragma unroll
    for (int kk = 0; kk < 2; ++kk) {
      bf16x8 as_ = *(const bf16x8*)&SsBuf[l15 * 72 + kk * 32 + quad * 8];
      #pragma unroll
      for (int tj = 0; tj < 4; ++tj)
        accr[tj] = __builtin_amdgcn_mfma_f32_16x16x32_bf16(bv[kk][tj], as_, accr[tj], 0, 0, 0);
    }
  };

  bf16_t* SsA = &Ss[w][0][0];   // lo unit
  bf16_t* SsB = &Ss[w][1][0];   // hi unit

  stage_tile(0, 0);
  for (int kt = 0; kt < niter; ++kt) {
    __syncthreads();  // drains this buffer's async loads; fences reuse
    if (kt + 1 < niter) stage_tile((kt + 1) & 1, kt + 1);
    const int buf = kt & 1;
    bf16x8 bk[2][4], bv[2][4];
    load_lds(Ks[buf], Vts[buf], bk, bv);
    if (kt <= r_lo) {
      // both units: independent MFMA streams, then overlapped Ss round-trips
      f32x4 s0[4], s1[4];
      sU(s0, qa[0], bk);
      sU(s1, qa[1], bk);
      wU(s0, kt == r_lo, SsA);
      wU(s1, kt == r_hi, SsB);
      pU(acc0, bv, SsA);
      pU(acc1, bv, SsB);
    } else {
      // hi unit only
      f32x4 s1[4];
      sU(s1, qa[1], bk);
      wU(s1, kt == r_hi, SsB);
      pU(acc1, bv, SsB);
    }
  }

  // epilogue: O^T regs -> out[b][pos][h*64+d], 4 d-contiguous per store
  #pragma unroll
  for (int tj = 0; tj < 4; ++tj) {
    bf16x4 p0, p1;
    #pragma unroll
    for (int r = 0; r < 4; ++r) { p0[r] = (bf16_t)acc0[tj][r]; p1[r] = (bf16_t)acc1[tj][r]; }
    int posA = r_lo * 64 + w * 16 + l15;
    int posB = r_hi * 64 + w * 16 + l15;
    int col = h * 64 + tj * 16 + quad * 4;
    *(bf16x4*)(out + ((size_t)b * 2048 + posA) * 1024 + col) = p0;
    *(bf16x4*)(out + ((size_t)b * 2048 + posB) * 1024 + col) = p1;
  }
}

// ---------------------------------------------------------------------------
// launch
// ---------------------------------------------------------------------------
extern "C" void kernel_launch(void* const* d_in, const int* in_sizes, int n_in,
                              void* d_out, int out_size, void* d_ws, size_t ws_size,
                              hipStream_t stream) {
  (void)in_sizes; (void)n_in; (void)out_size; (void)ws_size;
  const float* x     = (const float*)d_in[0];
  const float* ln1_g = (const float*)d_in[1];
  const float* ln1_b = (const float*)d_in[2];
  const float* w_qkv = (const float*)d_in[3];
  const float* w_out = (const float*)d_in[4];
  const float* ln2_g = (const float*)d_in[5];
  const float* ln2_b = (const float*)d_in[6];
  float* out = (float*)d_out;

  char* ws = (char*)d_ws;
  bf16_t* xn     = (bf16_t*)(ws + 0);          //  8,388,608  [4096,1024]
  bf16_t* wqkvT  = (bf16_t*)(ws + 8388608);    //  6,291,456  [3072,1024]
  bf16_t* woutT  = (bf16_t*)(ws + 14680064);   //  2,097,152  [1024,1024]
  bf16_t* qb     = (bf16_t*)(ws + 16777216);   //  8,388,608  [2,16,2048,64]
  bf16_t* kb     = (bf16_t*)(ws + 25165824);   //  8,388,608
  bf16_t* vTb    = (bf16_t*)(ws + 41943040);   //  8,388,608  [2,16,64,2048] (written by QKV epilogue)
  bf16_t* ao     = (bf16_t*)(ws + 50331648);   //  8,388,608  [4096,1024]
  bf16_t* zb0    = (bf16_t*)(ws + 58720256);   //  8,388,608  [4096,1024] bf16 partial
  bf16_t* zb1    = (bf16_t*)(ws + 67108864);   //  8,388,608  bf16 partial

  prep_kernel<<<5120, 256, 0, stream>>>(x, ln1_g, ln1_b, xn, w_qkv, wqkvT, w_out, woutT);
  gemm128_kernel<1, 1><<<dim3(24, 32), 256, 0, stream>>>(xn, wqkvT, qb, kb, vTb);
  attn_kernel<<<dim3(16, 16, 2), 256, 0, stream>>>(qb, kb, vTb, ao);
  gemm128_kernel<0, 2><<<dim3(8, 32, 2), 256, 0, stream>>>(ao, woutT, zb0, zb1, nullptr);
  ln2_kernel<<<4096, 256, 0, stream>>>(zb0, zb1, ln2_g, ln2_b, out);
}